// Round 11
// baseline (865.184 us; speedup 1.0000x reference)
//
#include <hip/hip_runtime.h>

// ---------------- problem constants ----------------
#define NROWS   131072
#define KDIM    1024
#define NLVL    4
#define SLOT_CAP 132096            // 131072 + 4*256 padding
#define NSB     516                // SLOT_CAP / 256 slot-blocks (max)
#define NNB     4                  // 1024 cols / 256
#define GRID_MAIN 2048             // fixed grid; blocks 0..extra-1 do 2 tiles

// ---------------- ws layout (bytes) ----------------
#define OFF_IDX  1024ull
#define OFF_PART (OFF_IDX + (size_t)SLOT_CAP * 4)
#define OFF_WT1  (OFF_PART + (size_t)SLOT_CAP * 64)
#define OFF_WT2  (OFF_WT1 + 8388608ull)
#define OFF_XBF  (OFF_WT2 + 8388608ull)
#define OFF_H1   (OFF_XBF + 268435456ull)

typedef __bf16 bf16x8 __attribute__((ext_vector_type(8)));
typedef float f32x4 __attribute__((ext_vector_type(4)));
typedef unsigned short u16x4 __attribute__((ext_vector_type(4)));

__device__ __forceinline__ unsigned short f2bf(float f) {
  unsigned int u = __float_as_uint(f);
  u += 0x7fffu + ((u >> 16) & 1u);       // RNE
  return (unsigned short)(u >> 16);
}

__device__ __forceinline__ void gld_lds16(const void* g, void* l) {
  __builtin_amdgcn_global_load_lds(
      (const __attribute__((address_space(1))) void*)g,
      (__attribute__((address_space(3))) void*)l, 16, 0, 0);
}

// meta layout (ints): [0..3]=counts [4..7]=cursors [8..11]=seg
// [12..15]=padded counts [16]=total tile-units

__global__ void k_hist(const int* __restrict__ levels, int n, int* __restrict__ meta) {
  __shared__ int h[NLVL];
  if (threadIdx.x < NLVL) h[threadIdx.x] = 0;
  __syncthreads();
  for (int t = blockIdx.x * blockDim.x + threadIdx.x; t < n; t += gridDim.x * blockDim.x)
    atomicAdd(&h[levels[t]], 1);
  __syncthreads();
  if (threadIdx.x < NLVL) atomicAdd(&meta[threadIdx.x], h[threadIdx.x]);
}

__global__ void k_seg(int* meta) {
  if (threadIdx.x == 0 && blockIdx.x == 0) {
    int s = 0;
    for (int l = 0; l < NLVL; ++l) {
      int pc = (meta[l] + 255) & ~255;
      meta[8 + l] = s;
      meta[12 + l] = pc;
      s += pc;
    }
    meta[16] = (s / 256) * NNB;      // total tile-units (>= 2048)
  }
}

__global__ void k_scatter(const int* __restrict__ levels, int n,
                          int* __restrict__ meta, int* __restrict__ idx) {
  __shared__ int h[NLVL], base[NLVL], cur[NLVL];
  int t = blockIdx.x * blockDim.x + threadIdx.x;
  if (threadIdx.x < NLVL) { h[threadIdx.x] = 0; cur[threadIdx.x] = 0; }
  __syncthreads();
  int lvl = 0;
  if (t < n) { lvl = levels[t]; atomicAdd(&h[lvl], 1); }
  __syncthreads();
  if (threadIdx.x < NLVL)
    base[threadIdx.x] = atomicAdd(&meta[4 + threadIdx.x], h[threadIdx.x]);
  __syncthreads();
  if (t < n) {
    int p = atomicAdd(&cur[lvl], 1);
    idx[meta[8 + lvl] + base[lvl] + p] = t;
  }
}

__global__ void k_cvt_x(const f32x4* __restrict__ x, u16x4* __restrict__ xb, int n4) {
  for (int t = blockIdx.x * blockDim.x + threadIdx.x; t < n4; t += gridDim.x * blockDim.x) {
    f32x4 v = x[t];
    u16x4 o;
    o[0] = f2bf(v[0]); o[1] = f2bf(v[1]); o[2] = f2bf(v[2]); o[3] = f2bf(v[3]);
    xb[t] = o;
  }
}

// transpose-convert W[lvl][k][n] (fp32) -> Wt[lvl][n][k] (bf16)
__global__ void k_twt(const float* __restrict__ W, unsigned short* __restrict__ Wt) {
  __shared__ float tile[32][33];
  int lvl = blockIdx.z;
  int k0 = blockIdx.x * 32, n0 = blockIdx.y * 32;
  int tx = threadIdx.x, ty = threadIdx.y;
  const float* Wp = W + (size_t)lvl * 1048576;
  unsigned short* Wtp = Wt + (size_t)lvl * 1048576;
#pragma unroll
  for (int i = 0; i < 4; ++i)
    tile[ty + i * 8][tx] = Wp[(size_t)(k0 + ty + i * 8) * 1024 + n0 + tx];
  __syncthreads();
#pragma unroll
  for (int i = 0; i < 4; ++i) {
    int nn = ty + i * 8;
    Wtp[(size_t)(n0 + nn) * 1024 + k0 + tx] = f2bf(tile[tx][nn]);
  }
}

// ---------------------------------------------------------------------------
// 256x256 grouped GEMM, BK=32, 16 waves (4m x 4n), per-wave 64x64, acc[4][4]
// f32x4, mfma 16x16x32 bf16, 3-deep LDS pipeline (96KB). Schedule = round-8
// (best known): phase = STG(t+2) | rd g1 | SB0 | rd g2 | lgkmcnt(4) | 4 MFMA
// | lgkmcnt(0) | 12 MFMA | vmcnt(2-equivalent: 4 loads/phase -> vmcnt(4)...
// here 2 gld/wave counted as in r8) | barrier.  (See r8 comments; ledger,
// tail-drain, asm-fenced barriers, both-sides chunk-XOR swizzle unchanged.)
//
// ROUND-11 CHANGE — pigeonhole tail fix: tile count = sum(ceil(c_l/256))*4
// ~ 2056 > 2048 = 8 rounds * 256 CUs, and at 1 resident block/CU that forced
// a 9th nearly-empty round (+11.6% makespan, r3..r10). Now grid = 2048 and
// blocks 0..extra-1 (extra = total-2048, first-dispatched, one per XCD)
// process TWO tiles sequentially; each tile's pipeline ends fully drained
// (vmcnt(0)+barrier in the tail) so iterations are independent. Makespan
// ~8.2 rounds. nrep is wave-uniform (bid+meta) -> barrier-safe.
// ---------------------------------------------------------------------------
#define BARRM   asm volatile("s_barrier" ::: "memory")
#define WAIT_L4 asm volatile("s_waitcnt lgkmcnt(4)" ::: "memory")
#define WAIT_L0 asm volatile("s_waitcnt lgkmcnt(0)" ::: "memory")
#define WAIT_V2 asm volatile("s_waitcnt vmcnt(2)" ::: "memory")
#define WAIT_V0 asm volatile("s_waitcnt vmcnt(0)" ::: "memory")
#define SB0     __builtin_amdgcn_sched_barrier(0)
#define PRIO(x) __builtin_amdgcn_s_setprio(x)

#define RDG1(p) { const char* w_ = lds + (p)*32768 + 16384 + offW; \
                  const char* x_ = lds + (p)*32768 + offX; \
  wf[0] = *(const bf16x8*)(w_);        wf[1] = *(const bf16x8*)(w_ + 1024);  \
  xf[0] = *(const bf16x8*)(x_);        xf[1] = *(const bf16x8*)(x_ + 1024); }
#define RDG2(p) { const char* w_ = lds + (p)*32768 + 16384 + offW; \
                  const char* x_ = lds + (p)*32768 + offX; \
  wf[2] = *(const bf16x8*)(w_ + 2048); wf[3] = *(const bf16x8*)(w_ + 3072); \
  xf[2] = *(const bf16x8*)(x_ + 2048); xf[3] = *(const bf16x8*)(x_ + 3072); }
#define MMA(nf_,mf_) acc[nf_][mf_] = __builtin_amdgcn_mfma_f32_16x16x32_bf16(wf[nf_], xf[mf_], acc[nf_][mf_], 0, 0, 0)
#define MMA_G1 { MMA(0,0); MMA(0,1); MMA(1,0); MMA(1,1); }
#define MMA_G2 { MMA(0,2); MMA(0,3); MMA(1,2); MMA(1,3); \
                 MMA(2,0); MMA(2,1); MMA(2,2); MMA(2,3); \
                 MMA(3,0); MMA(3,1); MMA(3,2); MMA(3,3); }
#define STG(p,t) { char* b_ = (char*)lds + (p)*32768 + (w << 10); \
  gld_lds16(xs0 + (t)*64, b_); \
  gld_lds16(ws0 + (t)*64, b_ + 16384); }

#define PHASE_CORE(p) \
  RDG1(p); SB0; RDG2(p); \
  WAIT_L4; SB0; \
  PRIO(1); MMA_G1; \
  WAIT_L0; SB0; \
  MMA_G2; PRIO(0);

template <int PASS>
__global__ __launch_bounds__(1024, 4) void k_gemm(
    const unsigned short* __restrict__ Asrc,
    const unsigned short* __restrict__ Wt,
    const float* __restrict__ bias,
    const float* __restrict__ w3,
    const int* __restrict__ meta,
    const int* __restrict__ idx,
    unsigned short* __restrict__ hout,
    float* __restrict__ partial) {
  __shared__ __align__(16) char lds[98304];

  const int bid = blockIdx.x;
  const int extra = meta[16] - GRID_MAIN;      // 0..16 overflow tiles
  const int nrep = (bid < extra) ? 2 : 1;

  const int tid = threadIdx.x;
  const int ln  = tid & 63;
  const int w   = tid >> 6;          // wave 0..15
  const int wm  = w & 3;             // m-quadrant (4 x 64 rows)
  const int wn  = w >> 2;            // n-quadrant (4 x 64 cols)
  const int l15 = ln & 15;

  // lane-only constants (tile-independent)
  const int srl  = ln >> 2;                         // staging sub-row 0..15
  const int cch  = (ln & 3) ^ ((ln >> 3) & 3);      // pre-swizzled src chunk
  const int xorc = ((ln >> 4) ^ ((l15 >> 1) & 3)) * 16;
  const int offX = (wm * 64 + l15) * 64 + xorc;
  const int offW = (wn * 64 + l15) * 64 + xorc;
  const int n_lo = (ln >> 4) * 4;

  for (int rep = 0; rep < nrep; ++rep) {
    // tile-unit id: main tiles 0..2047 via XCD-chunked bijection; overflow
    // tiles 2048..total-1 assigned to blocks 0..extra-1 (mostly-padding sbs).
    const int tu  = (rep == 0) ? bid : (GRID_MAIN + bid);
    const int swz = (tu < GRID_MAIN) ? ((tu & 7) * (GRID_MAIN / 8) + (tu >> 3)) : tu;
    const int nb = swz & 3;
    const int sb = swz >> 2;
    const int slotbase = sb * 256;
    int lvl;
    if      (slotbase < meta[9])  lvl = 0;
    else if (slotbase < meta[10]) lvl = 1;
    else if (slotbase < meta[11]) lvl = 2;
    else                          lvl = 3;

    // ---- staging pointers: wave w stages rows w*16..w*16+15 ----
    const int srow = w * 16 + srl;                  // 0..255
    int ar0;
    if (PASS == 1) ar0 = idx[slotbase + srow];
    else           ar0 = slotbase + srow;
    const char* xs0 = (const char*)Asrc + (size_t)ar0 * 2048 + cch * 16;
    const char* ws0 = (const char*)Wt + ((size_t)lvl << 21)
                      + (size_t)(nb * 256 + srow) * 2048 + cch * 16;

    const f32x4 vzero = {0.f, 0.f, 0.f, 0.f};
    f32x4 acc[4][4];
#pragma unroll
    for (int a = 0; a < 4; ++a)
#pragma unroll
      for (int b = 0; b < 4; ++b) acc[a][b] = vzero;
    bf16x8 wf[4], xf[4];

    // ---- prologue: stage tiles 0 and 1 (2 loads each) ----
    STG(0, 0); STG(1, 1);
    WAIT_V2;                         // tile0's 2 loads landed
    BARRM;

    // ---- steady state: phases 0..29, staging t+2 ----
#pragma unroll
    for (int t = 0; t < 30; ++t) {
      const int p  = t % 3;
      const int ps = (t + 2) % 3;
      STG(ps, t + 2);
      PHASE_CORE(p);
      WAIT_V2; BARRM;
    }

    // ---- tail: phase 30 (drain) and 31 ----
    PHASE_CORE(0);                   // tile 30, slot 0
    WAIT_V0; BARRM;                  // drain tile 31's loads
    PHASE_CORE(1);                   // tile 31, slot 1

    // ---- epilogue ----
    const float* bv = bias + lvl * 1024;

    if (PASS == 1) {
#pragma unroll
      for (int nf = 0; nf < 4; ++nf) {
#pragma unroll
        for (int mf = 0; mf < 4; ++mf) {
          int slot = slotbase + wm * 64 + mf * 16 + l15;
          int col = nb * 256 + wn * 64 + nf * 16 + n_lo;
          f32x4 bb = *(const f32x4*)&bv[col];
          f32x4 v = acc[nf][mf];
          u16x4 o;
#pragma unroll
          for (int r = 0; r < 4; ++r) o[r] = f2bf(fmaxf(v[r] + bb[r], 0.f));
          *(u16x4*)&hout[(size_t)slot * 1024 + col] = o;
        }
      }
    } else {
      const float* w3v = w3 + lvl * 1024;
      float ps4[4] = {0.f, 0.f, 0.f, 0.f};
#pragma unroll
      for (int mf = 0; mf < 4; ++mf) {
#pragma unroll
        for (int nf = 0; nf < 4; ++nf) {
          int col = nb * 256 + wn * 64 + nf * 16 + n_lo;
          f32x4 bb = *(const f32x4*)&bv[col];
          f32x4 ww = *(const f32x4*)&w3v[col];
          f32x4 v = acc[nf][mf];
#pragma unroll
          for (int r = 0; r < 4; ++r) ps4[mf] += fmaxf(v[r] + bb[r], 0.f) * ww[r];
        }
      }
#pragma unroll
      for (int mf = 0; mf < 4; ++mf) {
        float p = ps4[mf];
        p += __shfl_xor(p, 16);
        p += __shfl_xor(p, 32);
        if (ln < 16) {
          int slot = slotbase + wm * 64 + mf * 16 + ln;
          partial[(size_t)slot * 16 + nb * 4 + wn] = p;
        }
      }
    }
    // next rep (if any) starts from a fully drained state: the tail above
    // ended with vmcnt(0)+barrier before its final compute, and the
    // epilogue's LDS is untouched; rep-1 prologue re-barriers before reads.
    if (rep + 1 < nrep) { WAIT_V0; BARRM; }
  }
}

__global__ void k_final(const int* __restrict__ meta, const int* __restrict__ idx,
                        const float* __restrict__ partial, const float* __restrict__ b3,
                        float* __restrict__ out) {
  int t = blockIdx.x * blockDim.x + threadIdx.x;
  int total = meta[11] + meta[15];
  if (t >= total) return;
  int lvl;
  if (t < meta[9]) lvl = 0;
  else if (t < meta[10]) lvl = 1;
  else if (t < meta[11]) lvl = 2;
  else lvl = 3;
  int local = t - meta[8 + lvl];
  if (local >= meta[lvl]) return;  // padding slot
  int row = idx[t];
  const float* pp = partial + (size_t)t * 16;
  float s = 0.f;
#pragma unroll
  for (int j = 0; j < 16; ++j) s += pp[j];
  out[row] = s + b3[lvl];
}

extern "C" void kernel_launch(void* const* d_in, const int* in_sizes, int n_in,
                              void* d_out, int out_size, void* d_ws, size_t ws_size,
                              hipStream_t stream) {
  const float* x      = (const float*)d_in[0];
  const int*   levels = (const int*)d_in[1];
  const float* W1     = (const float*)d_in[2];
  const float* b1     = (const float*)d_in[3];
  const float* W2     = (const float*)d_in[4];
  const float* b2     = (const float*)d_in[5];
  const float* W3     = (const float*)d_in[6];
  const float* b3     = (const float*)d_in[7];
  float* out = (float*)d_out;

  char* ws = (char*)d_ws;
  int* meta = (int*)ws;
  int* idx = (int*)(ws + OFF_IDX);
  float* partial = (float*)(ws + OFF_PART);
  unsigned short* Wt1 = (unsigned short*)(ws + OFF_WT1);
  unsigned short* Wt2 = (unsigned short*)(ws + OFF_WT2);
  unsigned short* xb  = (unsigned short*)(ws + OFF_XBF);
  unsigned short* h1  = (unsigned short*)(ws + OFF_H1);

  // zero meta + idx (padding slots -> row 0, safe finite data)
  hipMemsetAsync(d_ws, 0, OFF_IDX + (size_t)SLOT_CAP * 4, stream);
  k_hist<<<256, 256, 0, stream>>>(levels, NROWS, meta);
  k_seg<<<1, 64, 0, stream>>>(meta);
  k_scatter<<<512, 256, 0, stream>>>(levels, NROWS, meta, idx);
  k_cvt_x<<<2048, 256, 0, stream>>>((const f32x4*)x, (u16x4*)xb, NROWS * (KDIM / 4));
  k_twt<<<dim3(32, 32, 4), dim3(32, 8), 0, stream>>>(W1, Wt1);
  k_twt<<<dim3(32, 32, 4), dim3(32, 8), 0, stream>>>(W2, Wt2);

  k_gemm<1><<<GRID_MAIN, 1024, 0, stream>>>(xb, Wt1, b1, nullptr, meta, idx, h1, nullptr);
  k_gemm<2><<<GRID_MAIN, 1024, 0, stream>>>(h1, Wt2, b2, W3, meta, idx, nullptr, partial);

  k_final<<<516, 256, 0, stream>>>(meta, idx, partial, b3, out);
}

// Round 12
// 780.269 us; speedup vs baseline: 1.1088x; 1.1088x over previous
//
#include <hip/hip_runtime.h>

// ---------------- problem constants ----------------
#define NROWS   131072
#define KDIM    1024
#define NLVL    4
#define SLOT_CAP 132096            // 131072 + 4*256 padding
#define NSB     516                // SLOT_CAP / 256 slot-blocks
#define NNB     4                  // 1024 cols / 256

// ---------------- ws layout (bytes) ----------------
#define OFF_IDX  1024ull
#define OFF_PART (OFF_IDX + (size_t)SLOT_CAP * 4)
#define OFF_WT1  (OFF_PART + (size_t)SLOT_CAP * 64)
#define OFF_WT2  (OFF_WT1 + 8388608ull)
#define OFF_XBF  (OFF_WT2 + 8388608ull)
#define OFF_H1   (OFF_XBF + 268435456ull)

typedef __bf16 bf16x8 __attribute__((ext_vector_type(8)));
typedef float f32x4 __attribute__((ext_vector_type(4)));
typedef unsigned short u16x4 __attribute__((ext_vector_type(4)));

__device__ __forceinline__ unsigned short f2bf(float f) {
  unsigned int u = __float_as_uint(f);
  u += 0x7fffu + ((u >> 16) & 1u);       // RNE
  return (unsigned short)(u >> 16);
}

__device__ __forceinline__ void gld_lds16(const void* g, void* l) {
  __builtin_amdgcn_global_load_lds(
      (const __attribute__((address_space(1))) void*)g,
      (__attribute__((address_space(3))) void*)l, 16, 0, 0);
}

// meta layout (ints): [0..3]=counts [4..7]=cursors [8..11]=seg [12..15]=padded counts

__global__ void k_hist(const int* __restrict__ levels, int n, int* __restrict__ meta) {
  __shared__ int h[NLVL];
  if (threadIdx.x < NLVL) h[threadIdx.x] = 0;
  __syncthreads();
  for (int t = blockIdx.x * blockDim.x + threadIdx.x; t < n; t += gridDim.x * blockDim.x)
    atomicAdd(&h[levels[t]], 1);
  __syncthreads();
  if (threadIdx.x < NLVL) atomicAdd(&meta[threadIdx.x], h[threadIdx.x]);
}

__global__ void k_seg(int* meta) {
  if (threadIdx.x == 0 && blockIdx.x == 0) {
    int s = 0;
    for (int l = 0; l < NLVL; ++l) {
      int pc = (meta[l] + 255) & ~255;
      meta[8 + l] = s;
      meta[12 + l] = pc;
      s += pc;
    }
  }
}

__global__ void k_scatter(const int* __restrict__ levels, int n,
                          int* __restrict__ meta, int* __restrict__ idx) {
  __shared__ int h[NLVL], base[NLVL], cur[NLVL];
  int t = blockIdx.x * blockDim.x + threadIdx.x;
  if (threadIdx.x < NLVL) { h[threadIdx.x] = 0; cur[threadIdx.x] = 0; }
  __syncthreads();
  int lvl = 0;
  if (t < n) { lvl = levels[t]; atomicAdd(&h[lvl], 1); }
  __syncthreads();
  if (threadIdx.x < NLVL)
    base[threadIdx.x] = atomicAdd(&meta[4 + threadIdx.x], h[threadIdx.x]);
  __syncthreads();
  if (t < n) {
    int p = atomicAdd(&cur[lvl], 1);
    idx[meta[8 + lvl] + base[lvl] + p] = t;
  }
}

__global__ void k_cvt_x(const f32x4* __restrict__ x, u16x4* __restrict__ xb, int n4) {
  for (int t = blockIdx.x * blockDim.x + threadIdx.x; t < n4; t += gridDim.x * blockDim.x) {
    f32x4 v = x[t];
    u16x4 o;
    o[0] = f2bf(v[0]); o[1] = f2bf(v[1]); o[2] = f2bf(v[2]); o[3] = f2bf(v[3]);
    xb[t] = o;
  }
}

// transpose-convert W[lvl][k][n] (fp32) -> Wt[lvl][n][k] (bf16)
__global__ void k_twt(const float* __restrict__ W, unsigned short* __restrict__ Wt) {
  __shared__ float tile[32][33];
  int lvl = blockIdx.z;
  int k0 = blockIdx.x * 32, n0 = blockIdx.y * 32;
  int tx = threadIdx.x, ty = threadIdx.y;
  const float* Wp = W + (size_t)lvl * 1048576;
  unsigned short* Wtp = Wt + (size_t)lvl * 1048576;
#pragma unroll
  for (int i = 0; i < 4; ++i)
    tile[ty + i * 8][tx] = Wp[(size_t)(k0 + ty + i * 8) * 1024 + n0 + tx];
  __syncthreads();
#pragma unroll
  for (int i = 0; i < 4; ++i) {
    int nn = ty + i * 8;
    Wtp[(size_t)(n0 + nn) * 1024 + k0 + tx] = f2bf(tile[tx][nn]);
  }
}

// ---------------------------------------------------------------------------
// ROUND-12: exact restoration of the round-8 kernel (best verified: 353us/
// GEMM = 785 TF, replay-deterministic, conflicts 0). r9/r10/r11 structural
// variants all regressed; r8 sits above the ceiling-adjusted expectation
// (m248 grouped-GEMM ceiling 848 TF / 1.116 ragged-grid quantization).
//
// 256x256 grouped GEMM, BK=32, 16 waves (4m x 4n), per-wave 64x64,
// mfma 16x16x32 bf16, acc[4][4] f32x4. 3-deep LDS pipeline, 96KB.
// Phase: STG(t+2) | ds_read g1(4) | ds_read g2(4) | lgkmcnt(4) | 4 MFMA (g1)
//   | lgkmcnt(0) | 12 MFMA | vmcnt(2) | barrier.
// Ledger (2 loads/wave/phase): prologue 4; tile j = loads #2j+1,2j+2; end of
// phase t vmcnt(2) => done through #2t+4 = tile t+1's last. TAIL: staging
// stops after phase 29; phase 30 ends vmcnt(0) (the counted window stops
// sliding when staging stops — round-5 lesson).
// Barriers are asm s_barrier with "memory" clobber (round-4 lesson).
// Swizzle: 64B rows, chunk-XOR on BOTH sides (pre-swizzled global source,
// linear gld_lds dest, same XOR on ds_read) -> conflict-free.
// XCD-chunked grid (nb innermost), 2064 blocks.
// ---------------------------------------------------------------------------
#define BARRM   asm volatile("s_barrier" ::: "memory")
#define WAIT_L4 asm volatile("s_waitcnt lgkmcnt(4)" ::: "memory")
#define WAIT_L0 asm volatile("s_waitcnt lgkmcnt(0)" ::: "memory")
#define WAIT_V2 asm volatile("s_waitcnt vmcnt(2)" ::: "memory")
#define WAIT_V0 asm volatile("s_waitcnt vmcnt(0)" ::: "memory")
#define SB0     __builtin_amdgcn_sched_barrier(0)
#define PRIO(x) __builtin_amdgcn_s_setprio(x)

#define RDG1(p) { const char* w_ = lds + (p)*32768 + 16384 + offW; \
                  const char* x_ = lds + (p)*32768 + offX; \
  wf[0] = *(const bf16x8*)(w_);        wf[1] = *(const bf16x8*)(w_ + 1024);  \
  xf[0] = *(const bf16x8*)(x_);        xf[1] = *(const bf16x8*)(x_ + 1024); }
#define RDG2(p) { const char* w_ = lds + (p)*32768 + 16384 + offW; \
                  const char* x_ = lds + (p)*32768 + offX; \
  wf[2] = *(const bf16x8*)(w_ + 2048); wf[3] = *(const bf16x8*)(w_ + 3072); \
  xf[2] = *(const bf16x8*)(x_ + 2048); xf[3] = *(const bf16x8*)(x_ + 3072); }
#define MMA(nf_,mf_) acc[nf_][mf_] = __builtin_amdgcn_mfma_f32_16x16x32_bf16(wf[nf_], xf[mf_], acc[nf_][mf_], 0, 0, 0)
#define MMA_G1 { MMA(0,0); MMA(0,1); MMA(1,0); MMA(1,1); }
#define MMA_G2 { MMA(0,2); MMA(0,3); MMA(1,2); MMA(1,3); \
                 MMA(2,0); MMA(2,1); MMA(2,2); MMA(2,3); \
                 MMA(3,0); MMA(3,1); MMA(3,2); MMA(3,3); }
#define STG(p,t) { char* b_ = (char*)lds + (p)*32768 + (w << 10); \
  gld_lds16(xs0 + (t)*64, b_); \
  gld_lds16(ws0 + (t)*64, b_ + 16384); }

#define PHASE_CORE(p) \
  RDG1(p); SB0; RDG2(p); \
  WAIT_L4; SB0; \
  PRIO(1); MMA_G1; \
  WAIT_L0; SB0; \
  MMA_G2; PRIO(0);

template <int PASS>
__global__ __launch_bounds__(1024, 4) void k_gemm(
    const unsigned short* __restrict__ Asrc,
    const unsigned short* __restrict__ Wt,
    const float* __restrict__ bias,
    const float* __restrict__ w3,
    const int* __restrict__ meta,
    const int* __restrict__ idx,
    unsigned short* __restrict__ hout,
    float* __restrict__ partial) {
  __shared__ __align__(16) char lds[98304];

  // XCD-chunked bijective swizzle over NSB*4 = 2064 blocks (2064 % 8 == 0).
  const int bid = blockIdx.x;
  const int swz = (bid & 7) * (NSB * NNB / 8) + (bid >> 3);
  const int nb = swz & 3;
  const int sb = swz >> 2;
  const int slotbase = sb * 256;
  if (slotbase >= meta[11] + meta[15]) return;
  int lvl;
  if      (slotbase < meta[9])  lvl = 0;
  else if (slotbase < meta[10]) lvl = 1;
  else if (slotbase < meta[11]) lvl = 2;
  else                          lvl = 3;

  const int tid = threadIdx.x;
  const int ln  = tid & 63;
  const int w   = tid >> 6;          // wave 0..15
  const int wm  = w & 3;             // m-quadrant (4 x 64 rows)
  const int wn  = w >> 2;            // n-quadrant (4 x 64 cols)
  const int l15 = ln & 15;

  // ---- staging lane constants: wave w stages X row & W row w*16+(ln>>2) ----
  const int srow = w * 16 + (ln >> 2);              // 0..255
  const int cch  = (ln & 3) ^ ((ln >> 3) & 3);      // pre-swizzled source chunk
  int ar0;
  if (PASS == 1) ar0 = idx[slotbase + srow];
  else           ar0 = slotbase + srow;
  const char* xs0 = (const char*)Asrc + (size_t)ar0 * 2048 + cch * 16;
  const char* ws0 = (const char*)Wt + ((size_t)lvl << 21)
                    + (size_t)(nb * 256 + srow) * 2048 + cch * 16;

  // ---- fragment read offsets (same XOR; +16 rows = +1024B) ----
  const int xorc = ((ln >> 4) ^ ((l15 >> 1) & 3)) * 16;
  const int offX = (wm * 64 + l15) * 64 + xorc;
  const int offW = (wn * 64 + l15) * 64 + xorc;

  const f32x4 vzero = {0.f, 0.f, 0.f, 0.f};
  f32x4 acc[4][4];
#pragma unroll
  for (int a = 0; a < 4; ++a)
#pragma unroll
    for (int b = 0; b < 4; ++b) acc[a][b] = vzero;
  bf16x8 wf[4], xf[4];

  // ---- prologue: stage tiles 0 and 1 (2 loads each) ----
  STG(0, 0); STG(1, 1);
  WAIT_V2;                           // tile0's 2 loads landed
  BARRM;

  // ---- steady state: phases 0..29, staging t+2 ----
#pragma unroll
  for (int t = 0; t < 30; ++t) {
    const int p  = t % 3;
    const int ps = (t + 2) % 3;
    STG(ps, t + 2);
    PHASE_CORE(p);
    WAIT_V2; BARRM;
  }

  // ---- tail: phase 30 (drain) and 31 ----
  PHASE_CORE(0);                     // tile 30, slot 0
  WAIT_V0; BARRM;                    // drain loads #63,64
  PHASE_CORE(1);                     // tile 31, slot 1

  // ---- epilogue ----
  const float* bv = bias + lvl * 1024;
  const int n_lo = (ln >> 4) * 4;

  if (PASS == 1) {
#pragma unroll
    for (int nf = 0; nf < 4; ++nf) {
#pragma unroll
      for (int mf = 0; mf < 4; ++mf) {
        int slot = slotbase + wm * 64 + mf * 16 + l15;
        int col = nb * 256 + wn * 64 + nf * 16 + n_lo;
        f32x4 bb = *(const f32x4*)&bv[col];
        f32x4 v = acc[nf][mf];
        u16x4 o;
#pragma unroll
        for (int r = 0; r < 4; ++r) o[r] = f2bf(fmaxf(v[r] + bb[r], 0.f));
        *(u16x4*)&hout[(size_t)slot * 1024 + col] = o;
      }
    }
  } else {
    const float* w3v = w3 + lvl * 1024;
    float ps4[4] = {0.f, 0.f, 0.f, 0.f};
#pragma unroll
    for (int mf = 0; mf < 4; ++mf) {
#pragma unroll
      for (int nf = 0; nf < 4; ++nf) {
        int col = nb * 256 + wn * 64 + nf * 16 + n_lo;
        f32x4 bb = *(const f32x4*)&bv[col];
        f32x4 ww = *(const f32x4*)&w3v[col];
        f32x4 v = acc[nf][mf];
#pragma unroll
        for (int r = 0; r < 4; ++r) ps4[mf] += fmaxf(v[r] + bb[r], 0.f) * ww[r];
      }
    }
#pragma unroll
    for (int mf = 0; mf < 4; ++mf) {
      float p = ps4[mf];
      p += __shfl_xor(p, 16);
      p += __shfl_xor(p, 32);
      if (ln < 16) {
        int slot = slotbase + wm * 64 + mf * 16 + ln;
        partial[(size_t)slot * 16 + nb * 4 + wn] = p;
      }
    }
  }
}

__global__ void k_final(const int* __restrict__ meta, const int* __restrict__ idx,
                        const float* __restrict__ partial, const float* __restrict__ b3,
                        float* __restrict__ out) {
  int t = blockIdx.x * blockDim.x + threadIdx.x;
  int total = meta[11] + meta[15];
  if (t >= total) return;
  int lvl;
  if (t < meta[9]) lvl = 0;
  else if (t < meta[10]) lvl = 1;
  else if (t < meta[11]) lvl = 2;
  else lvl = 3;
  int local = t - meta[8 + lvl];
  if (local >= meta[lvl]) return;  // padding slot
  int row = idx[t];
  const float* pp = partial + (size_t)t * 16;
  float s = 0.f;
#pragma unroll
  for (int j = 0; j < 16; ++j) s += pp[j];
  out[row] = s + b3[lvl];
}

extern "C" void kernel_launch(void* const* d_in, const int* in_sizes, int n_in,
                              void* d_out, int out_size, void* d_ws, size_t ws_size,
                              hipStream_t stream) {
  const float* x      = (const float*)d_in[0];
  const int*   levels = (const int*)d_in[1];
  const float* W1     = (const float*)d_in[2];
  const float* b1     = (const float*)d_in[3];
  const float* W2     = (const float*)d_in[4];
  const float* b2     = (const float*)d_in[5];
  const float* W3     = (const float*)d_in[6];
  const float* b3     = (const float*)d_in[7];
  float* out = (float*)d_out;

  char* ws = (char*)d_ws;
  int* meta = (int*)ws;
  int* idx = (int*)(ws + OFF_IDX);
  float* partial = (float*)(ws + OFF_PART);
  unsigned short* Wt1 = (unsigned short*)(ws + OFF_WT1);
  unsigned short* Wt2 = (unsigned short*)(ws + OFF_WT2);
  unsigned short* xb  = (unsigned short*)(ws + OFF_XBF);
  unsigned short* h1  = (unsigned short*)(ws + OFF_H1);

  // zero meta + idx (padding slots -> row 0, safe finite data)
  hipMemsetAsync(d_ws, 0, OFF_IDX + (size_t)SLOT_CAP * 4, stream);
  k_hist<<<256, 256, 0, stream>>>(levels, NROWS, meta);
  k_seg<<<1, 64, 0, stream>>>(meta);
  k_scatter<<<512, 256, 0, stream>>>(levels, NROWS, meta, idx);
  k_cvt_x<<<2048, 256, 0, stream>>>((const f32x4*)x, (u16x4*)xb, NROWS * (KDIM / 4));
  k_twt<<<dim3(32, 32, 4), dim3(32, 8), 0, stream>>>(W1, Wt1);
  k_twt<<<dim3(32, 32, 4), dim3(32, 8), 0, stream>>>(W2, Wt2);

  k_gemm<1><<<NSB * NNB, 1024, 0, stream>>>(xb, Wt1, b1, nullptr, meta, idx, h1, nullptr);
  k_gemm<2><<<NSB * NNB, 1024, 0, stream>>>(h1, Wt2, b2, W3, meta, idx, nullptr, partial);

  k_final<<<516, 256, 0, stream>>>(meta, idx, partial, b3, out);
}